// Round 7
// baseline (278.706 us; speedup 1.0000x reference)
//
#include <hip/hip_runtime.h>

#define T_ 4
#define S_ 2048
#define D_ 768
#define SD_ (S_ * D_)          // 1572864
#define TSD_ (T_ * SD_)        // 6291456
#define H_ 12
#define HD_ 64
#define PLANE_BYTES 2359296u   // 4 planes * 768 * 768 int8 per weight matrix

typedef int int32x4 __attribute__((ext_vector_type(4)));

// A-fragment-order byte address for logical element (m, k) of an Mx768 int8
// matrix: chunk (m>>4, k>>6) is 1024B; within: quad*256 + (m&15)*16 + (k&15).
// A wave's MFMA A-frag load is then chunkbase + lane*16 (contiguous 1KB).
__device__ __forceinline__ size_t frag_addr(int m, int d) {
    return ((size_t)(m >> 4) * 12 + (d >> 6)) * 1024 +
           (size_t)(((d >> 4) & 3) * 256 + (m & 15) * 16 + (d & 15));
}

// ---------------------------------------------------------------------------
// 0) Fused: y<4 -> pack weight matrix y (B-fragment order, 4 digit planes);
//    y==4 -> if_node over x -> init spikes in A-fragment order.
// ---------------------------------------------------------------------------
__global__ __launch_bounds__(256) void k_prep_all(const float* __restrict__ wq,
                                                  const float* __restrict__ wk,
                                                  const float* __restrict__ wv,
                                                  const float* __restrict__ wo,
                                                  const float* __restrict__ x,
                                                  unsigned char* __restrict__ Bp,
                                                  unsigned char* __restrict__ Sx) {
    if (blockIdx.y < 4) {
        const float* W = (blockIdx.y == 0) ? wq : (blockIdx.y == 1) ? wk
                       : (blockIdx.y == 2) ? wv : wo;
        unsigned char* out = Bp + (size_t)blockIdx.y * PLANE_BYTES;
        int idx = blockIdx.x * 256 + threadIdx.x;      // dword id, < 589824
        int j0 = idx & 3;
        int lane = (idx >> 2) & 63;
        int kb = (idx >> 8) % 12;
        int rest = (idx >> 8) / 12;
        int nbg = rest % 48;
        int p = rest / 48;
        int n = nbg * 16 + (lane & 15);
        int kbase = kb * 64 + (lane >> 4) * 16 + j0 * 4;
        unsigned int packed = 0;
#pragma unroll
        for (int jj = 0; jj < 4; jj++) {
            float w = W[(size_t)(kbase + jj) * D_ + n];
            int u = (int)rintf(w * 1073741824.0f);      // w * 2^30, |.| < 2^28
            for (int i = 0; i < p; i++) u = (u + 128) >> 8;
            packed |= ((unsigned int)(u & 255)) << (8 * jj);
        }
        *(unsigned int*)(out + (size_t)idx * 4) = packed;
    } else {
        int i = blockIdx.x * 256 + threadIdx.x;
        int idx = i * 4;
        if (idx >= SD_) return;
        int s = idx / D_;
        int d = idx % D_;
        double v[4] = {0.0, 0.0, 0.0, 0.0};
#pragma unroll
        for (int t = 0; t < T_; t++) {
            float4 xt = *(const float4*)(x + (size_t)t * SD_ + idx);
            float xs[4] = {xt.x, xt.y, xt.z, xt.w};
            uchar4 sp;
            unsigned char* so = &sp.x;
#pragma unroll
            for (int j = 0; j < 4; j++) {
                v[j] += (double)xs[j];
                unsigned char ss = (v[j] >= 1.0) ? 1 : 0;
                so[j] = ss;
                if (ss) v[j] = 0.0;
            }
            *(uchar4*)(Sx + frag_addr(t * S_ + s, d)) = sp;
        }
    }
}

// ---------------------------------------------------------------------------
// 2) i8 MFMA GEMM, exact fixed-point. NO LDS, NO BARRIERS: A and B are both
//    in MFMA fragment order in global; each wave streams its fragments
//    directly into registers with 1-kstep register double-buffering.
//    Block 256 thr = 4 waves 2x2 (wm,wn); tile 128M x 64N; wave 64M x 32N x
//    4 planes (acc = 128 AGPR). Redundant loads across wave pairs hit L1/L2.
// ---------------------------------------------------------------------------
__global__ __launch_bounds__(256, 2) void k_gemm_i8(
    const unsigned char* __restrict__ A,   // fragment-order spikes
    const unsigned char* __restrict__ Bp,  // packed digit planes (frag order)
    const unsigned char* __restrict__ Ms,  // mask [T][768] or nullptr
    float* __restrict__ C0, float* __restrict__ C1, float* __restrict__ C2,
    int bzoff) {
    int z = blockIdx.z;
    const unsigned char* B = Bp + (size_t)(bzoff + z) * PLANE_BYTES;
    float* C = (z == 0) ? C0 : (z == 1) ? C1 : C2;

    int tid = threadIdx.x;
    int lane = tid & 63;
    int w = tid >> 6;                 // wave 0..3
    int wm = w >> 1;                  // 0..1
    int wn = w & 1;                   // 0..1
    int row0 = blockIdx.x * 128;
    int tI = row0 >> 11;              // uniform t for this block
    int n0 = blockIdx.y * 64;
    int nbg0 = blockIdx.y * 4 + wn * 2;
    int col = lane & 15;
    int quad = lane >> 4;

    int32x4 zerov = {0, 0, 0, 0};
    int32x4 acc[4][2][4];             // [mb][nb][p]
#pragma unroll
    for (int mb = 0; mb < 4; mb++)
#pragma unroll
        for (int nb = 0; nb < 2; nb++)
#pragma unroll
            for (int p = 0; p < 4; p++) acc[mb][nb][p] = zerov;

    // A: wave covers rows row0 + wm*64 .. +63 -> chunk rows (row0>>4)+wm*4+mb
    const unsigned char* Ab =
        A + ((size_t)((row0 >> 4) + wm * 4) * 12) * 1024 + lane * 16;
    // B chunk (p, nb) at kb: ((p*48 + nbg0 + nb)*12 + kb)*1024
    const unsigned char* Bb = B + lane * 16;

    int32x4 a[2][4], b[2][8];
#pragma unroll
    for (int mb = 0; mb < 4; mb++)
        a[0][mb] = *(const int32x4*)(Ab + (size_t)mb * 12288);
#pragma unroll
    for (int q = 0; q < 8; q++) {
        int p = q >> 1, nb = q & 1;
        b[0][q] = *(const int32x4*)(
            Bb + (size_t)((p * 48 + nbg0 + nb) * 12) * 1024);
    }

    for (int kb = 0; kb < 12; kb++) {
        int cur = kb & 1, nxt = 1 - cur;
        int kn = (kb < 11) ? kb + 1 : kb;
        // prefetch kstep kn into the other register buffer (no barrier dep)
#pragma unroll
        for (int mb = 0; mb < 4; mb++)
            a[nxt][mb] = *(const int32x4*)(
                Ab + (size_t)mb * 12288 + (size_t)kn * 1024);
#pragma unroll
        for (int q = 0; q < 8; q++) {
            int p = q >> 1, nb = q & 1;
            b[nxt][q] = *(const int32x4*)(
                Bb + (size_t)((p * 48 + nbg0 + nb) * 12 + kn) * 1024);
        }
        int32x4 af[4];
#pragma unroll
        for (int mb = 0; mb < 4; mb++) af[mb] = a[cur][mb];
        if (Ms) {
            int32x4 mv = *(const int32x4*)(Ms + tI * D_ + kb * 64 + quad * 16);
#pragma unroll
            for (int mb = 0; mb < 4; mb++) af[mb] &= mv;
        }
#pragma unroll
        for (int p = 0; p < 4; p++)
#pragma unroll
            for (int nb = 0; nb < 2; nb++) {
                int32x4 bf = b[cur][p * 2 + nb];
#pragma unroll
                for (int mb = 0; mb < 4; mb++)
                    acc[mb][nb][p] = __builtin_amdgcn_mfma_i32_16x16x64_i8(
                        af[mb], bf, acc[mb][nb][p], 0, 0, 0);
            }
    }

#pragma unroll
    for (int mb = 0; mb < 4; mb++)
#pragma unroll
        for (int nb = 0; nb < 2; nb++)
#pragma unroll
            for (int r = 0; r < 4; r++) {
                long t = (long)acc[mb][nb][0][r] + ((long)acc[mb][nb][1][r] << 8)
                       + ((long)acc[mb][nb][2][r] << 16)
                       + ((long)acc[mb][nb][3][r] << 24);
                float v = (float)((double)t * (1.0 / 1073741824.0));
                int rr = row0 + wm * 64 + mb * 16 + quad * 4 + r;
                int cc = n0 + wn * 32 + nb * 16 + col;
                C[(size_t)rr * D_ + cc] = v;
            }
}

// ---------------------------------------------------------------------------
// 3) Fused BatchNorm1d (fp64 stats over T x D) + if_node (fp64).
//    Reads fp32 GEMM outputs; writes int8 spikes in A-fragment order.
// ---------------------------------------------------------------------------
__global__ __launch_bounds__(256) void k_bn_if(const float* __restrict__ Qf,
                                               const float* __restrict__ Kf,
                                               const float* __restrict__ Vf,
                                               unsigned char* __restrict__ Qs,
                                               unsigned char* __restrict__ Ks,
                                               unsigned char* __restrict__ Vs) {
    int s = blockIdx.x;
    int y = blockIdx.y;
    const float* X = (y == 0) ? Qf : (y == 1) ? Kf : Vf;
    unsigned char* Sp = (y == 0) ? Qs : (y == 1) ? Ks : Vs;

    __shared__ float buf[T_][D_];
    __shared__ double red[16];

    int tid = threadIdx.x;
    double sum = 0.0, sumsq = 0.0;
#pragma unroll
    for (int t = 0; t < T_; t++) {
        for (int d = tid; d < D_; d += 256) {
            float v = X[(size_t)t * SD_ + (size_t)s * D_ + d];
            buf[t][d] = v;
            double dv = (double)v;
            sum += dv;
            sumsq += dv * dv;
        }
    }
#pragma unroll
    for (int off = 32; off > 0; off >>= 1) {
        sum += __shfl_down(sum, off);
        sumsq += __shfl_down(sumsq, off);
    }
    int lane = tid & 63, wv = tid >> 6;
    if (lane == 0) { red[wv] = sum; red[4 + wv] = sumsq; }
    __syncthreads();
    if (tid == 0) {
        double s4 = red[0] + red[1] + red[2] + red[3];
        double q4 = red[4] + red[5] + red[6] + red[7];
        double mean = s4 / 3072.0;
        double var = q4 / 3072.0 - mean * mean;
        red[8] = mean;
        red[9] = 1.0 / sqrt(var + 1e-5);
    }
    __syncthreads();
    double mean = red[8], rstd = red[9];
    for (int d = tid; d < D_; d += 256) {
        double v = 0.0;
#pragma unroll
        for (int t = 0; t < T_; t++) {
            double xn = ((double)buf[t][d] - mean) * rstd;
            v += xn;
            int sp = (v >= 1.0) ? 1 : 0;
            Sp[frag_addr(t * S_ + s, d)] = (unsigned char)sp;
            if (sp) v = 0.0;
        }
    }
}

// ---------------------------------------------------------------------------
// 4) QK[t,h,d] = sum_s q&k over fragment-order spikes. One block per (t,h);
//    head h's data = 128 chunks of 1KB at stride 12KB. Bytewise AND + packed
//    byte accumulate (max 32 per byte, no carry), LDS reduce, no atomics.
// ---------------------------------------------------------------------------
__global__ __launch_bounds__(256) void k_qk(const unsigned char* __restrict__ Qs,
                                            const unsigned char* __restrict__ Ks,
                                            float* __restrict__ QK) {
    int t = blockIdx.x / H_;
    int h = blockIdx.x % H_;
    int lane = threadIdx.x & 63;
    int w = threadIdx.x >> 6;
    size_t base = ((size_t)t * 128 * 12 + h) * 1024 + lane * 16;
    uint4 acc = make_uint4(0, 0, 0, 0);
    for (int c = w; c < 128; c += 4) {
        uint4 q = *(const uint4*)(Qs + base + (size_t)c * 12288);
        uint4 k = *(const uint4*)(Ks + base + (size_t)c * 12288);
        acc.x += q.x & k.x;
        acc.y += q.y & k.y;
        acc.z += q.z & k.z;
        acc.w += q.w & k.w;
    }
    __shared__ unsigned int part[4][64][4];
    part[w][lane][0] = acc.x;
    part[w][lane][1] = acc.y;
    part[w][lane][2] = acc.z;
    part[w][lane][3] = acc.w;
    __syncthreads();
    if (threadIdx.x < 64) {
        int quad = threadIdx.x >> 4;
        int rem = threadIdx.x & 15;
        int dw = rem >> 2;
        int b = rem & 3;
        unsigned int tot = 0;
#pragma unroll
        for (int ww = 0; ww < 4; ww++)
            for (int cc = 0; cc < 16; cc++)
                tot += (part[ww][quad * 16 + cc][dw] >> (8 * b)) & 255u;
        QK[t * D_ + h * HD_ + quad * 16 + dw * 4 + b] = (float)tot;
    }
}

// ---------------------------------------------------------------------------
// 5) if_node over T on QK (exact integers) -> int8 mask QKm[t][768].
// ---------------------------------------------------------------------------
__global__ __launch_bounds__(256) void k_if_qk(const float* __restrict__ QK,
                                               unsigned char* __restrict__ QKm) {
    int j = blockIdx.x * 256 + threadIdx.x;
    if (j >= D_) return;
    float v = 0.f;
#pragma unroll
    for (int t = 0; t < T_; t++) {
        v += QK[t * D_ + j];
        unsigned char sp = (v >= 1.0f) ? 1 : 0;
        QKm[t * D_ + j] = sp;
        if (sp) v = 0.f;
    }
}

// ---------------------------------------------------------------------------
// 6) Final BatchNorm1d (fp64 stats), writes fp32 to d_out.
// ---------------------------------------------------------------------------
__global__ __launch_bounds__(256) void k_bn_out(const float* __restrict__ Xin,
                                                float* __restrict__ out) {
    int s = blockIdx.x;
    __shared__ float buf[T_][D_];
    __shared__ double red[16];
    int tid = threadIdx.x;
    double sum = 0.0, sumsq = 0.0;
#pragma unroll
    for (int t = 0; t < T_; t++) {
        for (int d = tid; d < D_; d += 256) {
            float v = Xin[(size_t)t * SD_ + (size_t)s * D_ + d];
            buf[t][d] = v;
            double dv = (double)v;
            sum += dv;
            sumsq += dv * dv;
        }
    }
#pragma unroll
    for (int off = 32; off > 0; off >>= 1) {
        sum += __shfl_down(sum, off);
        sumsq += __shfl_down(sumsq, off);
    }
    int lane = tid & 63, wv = tid >> 6;
    if (lane == 0) { red[wv] = sum; red[4 + wv] = sumsq; }
    __syncthreads();
    if (tid == 0) {
        double s4 = red[0] + red[1] + red[2] + red[3];
        double q4 = red[4] + red[5] + red[6] + red[7];
        double mean = s4 / 3072.0;
        double var = q4 / 3072.0 - mean * mean;
        red[8] = mean;
        red[9] = 1.0 / sqrt(var + 1e-5);
    }
    __syncthreads();
    double mean = red[8], rstd = red[9];
    for (int d = tid; d < D_; d += 256) {
#pragma unroll
        for (int t = 0; t < T_; t++) {
            double v = (double)buf[t][d];
            out[(size_t)t * SD_ + (size_t)s * D_ + d] =
                (float)((v - mean) * rstd);
        }
    }
}

// ---------------------------------------------------------------------------
extern "C" void kernel_launch(void* const* d_in, const int* in_sizes, int n_in,
                              void* d_out, int out_size, void* d_ws,
                              size_t ws_size, hipStream_t stream) {
    const float* x  = (const float*)d_in[0];
    const float* wq = (const float*)d_in[1];
    const float* wk = (const float*)d_in[2];
    const float* wv = (const float*)d_in[3];
    const float* wo = (const float*)d_in[4];
    float* out = (float*)d_out;

    float* ws  = (float*)d_ws;
    float* Qf  = ws;                         // pre-BN Q, then GEMM2 out
    float* Kf  = ws + (size_t)TSD_;
    float* Vf  = ws + (size_t)2 * TSD_;
    float* QK  = ws + (size_t)3 * TSD_;      // 3072 floats
    unsigned char* QKm = (unsigned char*)(QK + T_ * D_);  // 3072 B mask (+pad)
    unsigned char* Sx  = QKm + 4096;         // init spikes (frag order); -> Qs
    unsigned char* Ks  = Sx + (size_t)TSD_;
    unsigned char* Vs  = Ks + (size_t)TSD_;
    unsigned char* Bp  = Vs + (size_t)TSD_;  // packed weights, 9.4 MB
    unsigned char* Qs  = Sx;                 // GEMM1 consumed Sx before bn_if

    // 0) pack weights + init spikes (fused)
    k_prep_all<<<dim3(589824 / 256, 5), 256, 0, stream>>>(wq, wk, wv, wo, x,
                                                          Bp, Sx);
    // 1) Q/K/V GEMMs (exact fixed-point; all operands streamed from global)
    k_gemm_i8<<<dim3(64, 12, 3), 256, 0, stream>>>(Sx, Bp, nullptr,
                                                   Qf, Kf, Vf, 0);
    // 2) BN + IF -> fragment-order int8 spikes (Qs aliases Sx)
    k_bn_if<<<dim3(S_, 3), 256, 0, stream>>>(Qf, Kf, Vf, Qs, Ks, Vs);
    // 3) talking-heads reduce over S (no atomics)
    k_qk<<<T_ * H_, 256, 0, stream>>>(Qs, Ks, QK);
    // 4) IF on QK -> int8 mask
    k_if_qk<<<3, 256, 0, stream>>>(QK, QKm);
    // 5) out_pre = (Vs & QKm) @ wo -> Qf   (mask fused into A-path)
    k_gemm_i8<<<dim3(64, 12, 1), 256, 0, stream>>>(Vs, Bp, QKm, Qf, Qf, Qf, 3);
    // 6) final BN -> d_out
    k_bn_out<<<S_, 256, 0, stream>>>(Qf, out);
}

// Round 8
// 246.485 us; speedup vs baseline: 1.1307x; 1.1307x over previous
//
#include <hip/hip_runtime.h>

#define T_ 4
#define S_ 2048
#define D_ 768
#define SD_ (S_ * D_)          // 1572864
#define TSD_ (T_ * SD_)        // 6291456
#define H_ 12
#define HD_ 64
#define PLANE_BYTES 2359296u   // 4 planes * 768 * 768 int8 per weight matrix

typedef int int32x4 __attribute__((ext_vector_type(4)));

// async global->LDS, 16B per lane; LDS dest = wave-uniform base + lane*16
__device__ __forceinline__ void cp16(unsigned char* lds, const unsigned char* g) {
    __builtin_amdgcn_global_load_lds(
        (const __attribute__((address_space(1))) unsigned int*)g,
        (__attribute__((address_space(3))) unsigned int*)lds, 16, 0, 0);
}

// Fragment order for an Mx768 int8 matrix: chunk (m>>4, k>>6) is 1024B;
// within: (k>>4 &3)*256 + (m&15)*16 + (k&15). Wave A-frag = chunk + lane*16.
__device__ __forceinline__ size_t frag_addr(int m, int d) {
    return ((size_t)(m >> 4) * 12 + (d >> 6)) * 1024 +
           (size_t)(((d >> 4) & 3) * 256 + (m & 15) * 16 + (d & 15));
}

// ---------------------------------------------------------------------------
// 0) y<4: pack weight matrix y -> B-fragment order, 4 digit planes, via LDS
//    repack (coalesced read + contiguous write). y==4 (x<384): if_node over x
//    -> init spikes, 16-d granules -> aligned uint4 stores in fragment order.
// ---------------------------------------------------------------------------
__global__ __launch_bounds__(256) void k_prep_all(const float* __restrict__ wq,
                                                  const float* __restrict__ wk,
                                                  const float* __restrict__ wv,
                                                  const float* __restrict__ wo,
                                                  const float* __restrict__ x,
                                                  unsigned char* __restrict__ Bp,
                                                  unsigned char* __restrict__ Sx) {
    __shared__ unsigned char wl[4096];
    int tid = threadIdx.x;
    if (blockIdx.y < 4) {
        const float* W = (blockIdx.y == 0) ? wq : (blockIdx.y == 1) ? wk
                       : (blockIdx.y == 2) ? wv : wo;
        unsigned char* out = Bp + (size_t)blockIdx.y * PLANE_BYTES;
        int c = blockIdx.x;            // 0..575
        int kb = c % 12;
        int nbg = c / 12;
        int k_loc = tid >> 2;
        int n_base = (tid & 3) * 4;
        float4 w4 = *(const float4*)(
            W + (size_t)(kb * 64 + k_loc) * D_ + nbg * 16 + n_base);
        float wsv[4] = {w4.x, w4.y, w4.z, w4.w};
#pragma unroll
        for (int j = 0; j < 4; j++) {
            int n_loc = n_base + j;
            int u = (int)rintf(wsv[j] * 1073741824.0f);   // w * 2^30
#pragma unroll
            for (int p = 0; p < 4; p++) {
                wl[p * 1024 + (n_loc + 16 * (k_loc >> 4)) * 16 + (k_loc & 15)] =
                    (unsigned char)(u & 255);
                u = (u + 128) >> 8;                        // balanced peel
            }
        }
        __syncthreads();
        int p = tid >> 6;
        int lane = tid & 63;
        uint4 val = *(const uint4*)&wl[p * 1024 + lane * 16];
        *(uint4*)(out + (size_t)((p * 48 + nbg) * 12 + kb) * 1024 + lane * 16) =
            val;
    } else {
        if (blockIdx.x >= 384) return;
        int gid = blockIdx.x * 256 + tid;      // 98304 threads
        int s = gid / 48;
        int d0 = (gid % 48) * 16;
        double v[16];
#pragma unroll
        for (int j = 0; j < 16; j++) v[j] = 0.0;
#pragma unroll
        for (int t = 0; t < T_; t++) {
            union { uint4 u; unsigned char b[16]; } sp;
#pragma unroll
            for (int q = 0; q < 4; q++) {
                float4 xt = *(const float4*)(
                    x + (size_t)t * SD_ + (size_t)s * D_ + d0 + q * 4);
                float xs[4] = {xt.x, xt.y, xt.z, xt.w};
#pragma unroll
                for (int j = 0; j < 4; j++) {
                    int jj = q * 4 + j;
                    v[jj] += (double)xs[j];
                    unsigned char ss = (v[jj] >= 1.0) ? 1 : 0;
                    sp.b[jj] = ss;
                    if (ss) v[jj] = 0.0;
                }
            }
            *(uint4*)(Sx + frag_addr(t * S_ + s, d0)) = sp.u;
        }
    }
}

// ---------------------------------------------------------------------------
// 2) i8 MFMA GEMM, exact fixed-point. Hybrid: B LDS-staged (dbuf, shared by
//    4 waves, conflict-free lane*16 reads); A streamed from global fragment
//    order with register double-buffering (no barrier dependency).
//    Tile 128M x 64N; 4 waves 2x2; wave 64M x 32N x 4 planes (128 AGPR acc).
// ---------------------------------------------------------------------------
__global__ __launch_bounds__(256, 2) void k_gemm_i8(
    const unsigned char* __restrict__ A,   // fragment-order spikes
    const unsigned char* __restrict__ Bp,  // packed digit planes (frag order)
    const unsigned char* __restrict__ Ms,  // mask [T][768] or nullptr
    float* __restrict__ C0, float* __restrict__ C1, float* __restrict__ C2,
    int bzoff) {
    int z = blockIdx.z;
    const unsigned char* B = Bp + (size_t)(bzoff + z) * PLANE_BYTES;
    float* C = (z == 0) ? C0 : (z == 1) ? C1 : C2;

    __shared__ __align__(16) unsigned char bsm[2 * 16384];

    int tid = threadIdx.x;
    int lane = tid & 63;
    int w = tid >> 6;                 // wave 0..3
    int wm = w >> 1;                  // 0..1
    int wn = w & 1;                   // 0..1
    int row0 = blockIdx.x * 128;
    int tI = row0 >> 11;              // uniform t for this block
    int n0 = blockIdx.y * 64;
    int nbg0 = blockIdx.y * 4;
    int col = lane & 15;
    int quad = lane >> 4;

    int32x4 zerov = {0, 0, 0, 0};
    int32x4 acc[4][2][4];             // [mb][nb][p]
#pragma unroll
    for (int mb = 0; mb < 4; mb++)
#pragma unroll
        for (int nb = 0; nb < 2; nb++)
#pragma unroll
            for (int p = 0; p < 4; p++) acc[mb][nb][p] = zerov;

    // A chunk for (mb, kb): Ab + (mb*12 + kb)*1024
    const unsigned char* Ab =
        A + (size_t)((row0 >> 4) + wm * 4) * 12 * 1024 + lane * 16;

    auto stageB = [&](int buf, int kb) {
        unsigned char* bb = bsm + buf * 16384;
#pragma unroll
        for (int qi = 0; qi < 4; qi++) {
            int q = w * 4 + qi;           // chunk id: p = q>>2, nb = q&3
            int p = q >> 2, nb = q & 3;
            cp16(bb + q * 1024,
                 B + (size_t)((p * 48 + nbg0 + nb) * 12 + kb) * 1024 + lane * 16);
        }
    };

    int32x4 a[2][4];
#pragma unroll
    for (int mb = 0; mb < 4; mb++)
        a[0][mb] = *(const int32x4*)(Ab + (size_t)(mb * 12) * 1024);
    stageB(0, 0);
    __syncthreads();

    for (int kb = 0; kb < 12; kb++) {
        int cur = kb & 1;
        if (kb < 11) {
            stageB(1 - cur, kb + 1);
#pragma unroll
            for (int mb = 0; mb < 4; mb++)
                a[1 - cur][mb] = *(const int32x4*)(
                    Ab + (size_t)(mb * 12 + kb + 1) * 1024);
        }
        int32x4 af[4];
#pragma unroll
        for (int mb = 0; mb < 4; mb++) af[mb] = a[cur][mb];
        if (Ms) {
            int32x4 mv = *(const int32x4*)(Ms + tI * D_ + kb * 64 + quad * 16);
#pragma unroll
            for (int mb = 0; mb < 4; mb++) af[mb] &= mv;
        }
        const unsigned char* bb = bsm + cur * 16384;
#pragma unroll
        for (int p = 0; p < 4; p++)
#pragma unroll
            for (int nb = 0; nb < 2; nb++) {
                int32x4 bf = *(const int32x4*)(
                    bb + (size_t)(p * 4 + wn * 2 + nb) * 1024 + lane * 16);
#pragma unroll
                for (int mb = 0; mb < 4; mb++)
                    acc[mb][nb][p] = __builtin_amdgcn_mfma_i32_16x16x64_i8(
                        af[mb], bf, acc[mb][nb][p], 0, 0, 0);
            }
        __syncthreads();
    }

#pragma unroll
    for (int mb = 0; mb < 4; mb++)
#pragma unroll
        for (int nb = 0; nb < 2; nb++)
#pragma unroll
            for (int r = 0; r < 4; r++) {
                long t = (long)acc[mb][nb][0][r] + ((long)acc[mb][nb][1][r] << 8)
                       + ((long)acc[mb][nb][2][r] << 16)
                       + ((long)acc[mb][nb][3][r] << 24);
                float v = (float)((double)t * (1.0 / 1073741824.0));
                int rr = row0 + wm * 64 + mb * 16 + quad * 4 + r;
                int cc = n0 + wn * 32 + nb * 16 + col;
                C[(size_t)rr * D_ + cc] = v;
            }
}

// ---------------------------------------------------------------------------
// 3) Fused BatchNorm1d (fp64 stats over T x D) + if_node (fp64).
//    Spikes staged in LDS, then written as aligned 16B fragment granules.
// ---------------------------------------------------------------------------
__global__ __launch_bounds__(256) void k_bn_if(const float* __restrict__ Qf,
                                               const float* __restrict__ Kf,
                                               const float* __restrict__ Vf,
                                               unsigned char* __restrict__ Qs,
                                               unsigned char* __restrict__ Ks,
                                               unsigned char* __restrict__ Vs) {
    int s = blockIdx.x;
    int y = blockIdx.y;
    const float* X = (y == 0) ? Qf : (y == 1) ? Kf : Vf;
    unsigned char* Sp = (y == 0) ? Qs : (y == 1) ? Ks : Vs;

    __shared__ float buf[T_][D_];
    __shared__ double red[16];
    __shared__ unsigned char spk[T_ * D_];

    int tid = threadIdx.x;
    double sum = 0.0, sumsq = 0.0;
#pragma unroll
    for (int t = 0; t < T_; t++) {
        for (int d = tid; d < D_; d += 256) {
            float v = X[(size_t)t * SD_ + (size_t)s * D_ + d];
            buf[t][d] = v;
            double dv = (double)v;
            sum += dv;
            sumsq += dv * dv;
        }
    }
#pragma unroll
    for (int off = 32; off > 0; off >>= 1) {
        sum += __shfl_down(sum, off);
        sumsq += __shfl_down(sumsq, off);
    }
    int lane = tid & 63, wv = tid >> 6;
    if (lane == 0) { red[wv] = sum; red[4 + wv] = sumsq; }
    __syncthreads();
    if (tid == 0) {
        double s4 = red[0] + red[1] + red[2] + red[3];
        double q4 = red[4] + red[5] + red[6] + red[7];
        double mean = s4 / 3072.0;
        double var = q4 / 3072.0 - mean * mean;
        red[8] = mean;
        red[9] = 1.0 / sqrt(var + 1e-5);
    }
    __syncthreads();
    double mean = red[8], rstd = red[9];
    for (int d = tid; d < D_; d += 256) {
        double v = 0.0;
#pragma unroll
        for (int t = 0; t < T_; t++) {
            double xn = ((double)buf[t][d] - mean) * rstd;
            v += xn;
            int sp = (v >= 1.0) ? 1 : 0;
            spk[t * D_ + d] = (unsigned char)sp;
            if (sp) v = 0.0;
        }
    }
    __syncthreads();
    if (tid < 192) {
        int tt = tid / 48, gg = tid % 48;
        uint4 val = *(const uint4*)&spk[tt * D_ + gg * 16];
        size_t dst = ((size_t)(tt * 128 + (s >> 4)) * 12 + (gg >> 2)) * 1024 +
                     (size_t)((gg & 3) * 256 + (s & 15) * 16);
        *(uint4*)(Sp + dst) = val;
    }
}

// ---------------------------------------------------------------------------
// 4) QK[t,h,d] = sum_s q&k over fragment-order spikes. One block per (t,h).
// ---------------------------------------------------------------------------
__global__ __launch_bounds__(256) void k_qk(const unsigned char* __restrict__ Qs,
                                            const unsigned char* __restrict__ Ks,
                                            float* __restrict__ QK) {
    int t = blockIdx.x / H_;
    int h = blockIdx.x % H_;
    int lane = threadIdx.x & 63;
    int w = threadIdx.x >> 6;
    size_t base = ((size_t)t * 128 * 12 + h) * 1024 + lane * 16;
    uint4 acc = make_uint4(0, 0, 0, 0);
    for (int c = w; c < 128; c += 4) {
        uint4 q = *(const uint4*)(Qs + base + (size_t)c * 12288);
        uint4 k = *(const uint4*)(Ks + base + (size_t)c * 12288);
        acc.x += q.x & k.x;
        acc.y += q.y & k.y;
        acc.z += q.z & k.z;
        acc.w += q.w & k.w;
    }
    __shared__ unsigned int part[4][64][4];
    part[w][lane][0] = acc.x;
    part[w][lane][1] = acc.y;
    part[w][lane][2] = acc.z;
    part[w][lane][3] = acc.w;
    __syncthreads();
    if (threadIdx.x < 64) {
        int quad = threadIdx.x >> 4;
        int rem = threadIdx.x & 15;
        int dw = rem >> 2;
        int b = rem & 3;
        unsigned int tot = 0;
#pragma unroll
        for (int ww = 0; ww < 4; ww++)
            for (int cc = 0; cc < 16; cc++)
                tot += (part[ww][quad * 16 + cc][dw] >> (8 * b)) & 255u;
        QK[t * D_ + h * HD_ + quad * 16 + dw * 4 + b] = (float)tot;
    }
}

// ---------------------------------------------------------------------------
// 5) if_node over T on QK (exact integers) -> int8 mask QKm[t][768].
// ---------------------------------------------------------------------------
__global__ __launch_bounds__(256) void k_if_qk(const float* __restrict__ QK,
                                               unsigned char* __restrict__ QKm) {
    int j = blockIdx.x * 256 + threadIdx.x;
    if (j >= D_) return;
    float v = 0.f;
#pragma unroll
    for (int t = 0; t < T_; t++) {
        v += QK[t * D_ + j];
        unsigned char sp = (v >= 1.0f) ? 1 : 0;
        QKm[t * D_ + j] = sp;
        if (sp) v = 0.f;
    }
}

// ---------------------------------------------------------------------------
// 6) Final BatchNorm1d (fp64 stats), writes fp32 to d_out.
// ---------------------------------------------------------------------------
__global__ __launch_bounds__(256) void k_bn_out(const float* __restrict__ Xin,
                                                float* __restrict__ out) {
    int s = blockIdx.x;
    __shared__ float buf[T_][D_];
    __shared__ double red[16];
    int tid = threadIdx.x;
    double sum = 0.0, sumsq = 0.0;
#pragma unroll
    for (int t = 0; t < T_; t++) {
        for (int d = tid; d < D_; d += 256) {
            float v = Xin[(size_t)t * SD_ + (size_t)s * D_ + d];
            buf[t][d] = v;
            double dv = (double)v;
            sum += dv;
            sumsq += dv * dv;
        }
    }
#pragma unroll
    for (int off = 32; off > 0; off >>= 1) {
        sum += __shfl_down(sum, off);
        sumsq += __shfl_down(sumsq, off);
    }
    int lane = tid & 63, wv = tid >> 6;
    if (lane == 0) { red[wv] = sum; red[4 + wv] = sumsq; }
    __syncthreads();
    if (tid == 0) {
        double s4 = red[0] + red[1] + red[2] + red[3];
        double q4 = red[4] + red[5] + red[6] + red[7];
        double mean = s4 / 3072.0;
        double var = q4 / 3072.0 - mean * mean;
        red[8] = mean;
        red[9] = 1.0 / sqrt(var + 1e-5);
    }
    __syncthreads();
    double mean = red[8], rstd = red[9];
    for (int d = tid; d < D_; d += 256) {
#pragma unroll
        for (int t = 0; t < T_; t++) {
            double v = (double)buf[t][d];
            out[(size_t)t * SD_ + (size_t)s * D_ + d] =
                (float)((v - mean) * rstd);
        }
    }
}

// ---------------------------------------------------------------------------
extern "C" void kernel_launch(void* const* d_in, const int* in_sizes, int n_in,
                              void* d_out, int out_size, void* d_ws,
                              size_t ws_size, hipStream_t stream) {
    const float* x  = (const float*)d_in[0];
    const float* wq = (const float*)d_in[1];
    const float* wk = (const float*)d_in[2];
    const float* wv = (const float*)d_in[3];
    const float* wo = (const float*)d_in[4];
    float* out = (float*)d_out;

    float* ws  = (float*)d_ws;
    float* Qf  = ws;                         // pre-BN Q, then GEMM2 out
    float* Kf  = ws + (size_t)TSD_;
    float* Vf  = ws + (size_t)2 * TSD_;
    float* QK  = ws + (size_t)3 * TSD_;      // 3072 floats
    unsigned char* QKm = (unsigned char*)(QK + T_ * D_);  // 3072 B mask (+pad)
    unsigned char* Sx  = QKm + 4096;         // init spikes (frag order); -> Qs
    unsigned char* Ks  = Sx + (size_t)TSD_;
    unsigned char* Vs  = Ks + (size_t)TSD_;
    unsigned char* Bp  = Vs + (size_t)TSD_;  // packed weights, 9.4 MB
    unsigned char* Qs  = Sx;                 // GEMM1 consumed Sx before bn_if

    // 0) pack weights (LDS repack, coalesced) + init spikes
    k_prep_all<<<dim3(576, 5), 256, 0, stream>>>(wq, wk, wv, wo, x, Bp, Sx);
    // 1) Q/K/V GEMMs (A from global frag-order, B LDS dbuf)
    k_gemm_i8<<<dim3(64, 12, 3), 256, 0, stream>>>(Sx, Bp, nullptr,
                                                   Qf, Kf, Vf, 0);
    // 2) BN + IF -> fragment-order int8 spikes (Qs aliases Sx)
    k_bn_if<<<dim3(S_, 3), 256, 0, stream>>>(Qf, Kf, Vf, Qs, Ks, Vs);
    // 3) talking-heads reduce over S (no atomics)
    k_qk<<<T_ * H_, 256, 0, stream>>>(Qs, Ks, QK);
    // 4) IF on QK -> int8 mask
    k_if_qk<<<3, 256, 0, stream>>>(QK, QKm);
    // 5) out_pre = (Vs & QKm) @ wo -> Qf   (mask fused into A-path)
    k_gemm_i8<<<dim3(64, 12, 1), 256, 0, stream>>>(Vs, Bp, QKm, Qf, Qf, Qf, 3);
    // 6) final BN -> d_out
    k_bn_out<<<S_, 256, 0, stream>>>(Qf, out);
}

// Round 9
// 227.679 us; speedup vs baseline: 1.2241x; 1.0826x over previous
//
#include <hip/hip_runtime.h>

#define T_ 4
#define S_ 2048
#define D_ 768
#define SD_ (S_ * D_)          // 1572864
#define TSD_ (T_ * SD_)        // 6291456
#define H_ 12
#define HD_ 64
#define PLANE_BYTES 2359296u   // 4 planes * 768 * 768 int8 per weight matrix

typedef int int32x4 __attribute__((ext_vector_type(4)));

// async global->LDS, 16B per lane; LDS dest = wave-uniform base + lane*16
__device__ __forceinline__ void cp16(unsigned char* lds, const unsigned char* g) {
    __builtin_amdgcn_global_load_lds(
        (const __attribute__((address_space(1))) unsigned int*)g,
        (__attribute__((address_space(3))) unsigned int*)lds, 16, 0, 0);
}

// Fragment order for an Mx768 int8 matrix: chunk (m>>4, k>>6) is 1024B;
// within: (k>>4 &3)*256 + (m&15)*16 + (k&15). Wave A-frag = chunk + lane*16.
__device__ __forceinline__ size_t frag_addr(int m, int d) {
    return ((size_t)(m >> 4) * 12 + (d >> 6)) * 1024 +
           (size_t)(((d >> 4) & 3) * 256 + (m & 15) * 16 + (d & 15));
}

// ---------------------------------------------------------------------------
// 0) y<4: pack weight matrix y -> B-fragment order (LDS repack, coalesced).
//    y==4, x<384: if_node over x -> init spikes in fragment order.
//    y==4, 384<=x<432: zero the QKp presence accumulator (12288 words).
// ---------------------------------------------------------------------------
__global__ __launch_bounds__(256) void k_prep_all(const float* __restrict__ wq,
                                                  const float* __restrict__ wk,
                                                  const float* __restrict__ wv,
                                                  const float* __restrict__ wo,
                                                  const float* __restrict__ x,
                                                  unsigned char* __restrict__ Bp,
                                                  unsigned char* __restrict__ Sx,
                                                  unsigned int* __restrict__ QKp) {
    __shared__ unsigned char wl[4096];
    int tid = threadIdx.x;
    if (blockIdx.y < 4) {
        const float* W = (blockIdx.y == 0) ? wq : (blockIdx.y == 1) ? wk
                       : (blockIdx.y == 2) ? wv : wo;
        unsigned char* out = Bp + (size_t)blockIdx.y * PLANE_BYTES;
        int c = blockIdx.x;            // 0..575
        int kb = c % 12;
        int nbg = c / 12;
        int k_loc = tid >> 2;
        int n_base = (tid & 3) * 4;
        float4 w4 = *(const float4*)(
            W + (size_t)(kb * 64 + k_loc) * D_ + nbg * 16 + n_base);
        float wsv[4] = {w4.x, w4.y, w4.z, w4.w};
#pragma unroll
        for (int j = 0; j < 4; j++) {
            int n_loc = n_base + j;
            int u = (int)rintf(wsv[j] * 1073741824.0f);   // w * 2^30
#pragma unroll
            for (int p = 0; p < 4; p++) {
                wl[p * 1024 + (n_loc + 16 * (k_loc >> 4)) * 16 + (k_loc & 15)] =
                    (unsigned char)(u & 255);
                u = (u + 128) >> 8;                        // balanced peel
            }
        }
        __syncthreads();
        int p = tid >> 6;
        int lane = tid & 63;
        uint4 val = *(const uint4*)&wl[p * 1024 + lane * 16];
        *(uint4*)(out + (size_t)((p * 48 + nbg) * 12 + kb) * 1024 + lane * 16) =
            val;
    } else {
        if (blockIdx.x >= 384) {
            if (blockIdx.x < 432) {
                int idx = (blockIdx.x - 384) * 256 + tid;   // < 12288
                QKp[idx] = 0u;
            }
            return;
        }
        int gid = blockIdx.x * 256 + tid;      // 98304 threads
        int s = gid / 48;
        int d0 = (gid % 48) * 16;
        double v[16];
#pragma unroll
        for (int j = 0; j < 16; j++) v[j] = 0.0;
#pragma unroll
        for (int t = 0; t < T_; t++) {
            union { uint4 u; unsigned char b[16]; } sp;
#pragma unroll
            for (int q = 0; q < 4; q++) {
                float4 xt = *(const float4*)(
                    x + (size_t)t * SD_ + (size_t)s * D_ + d0 + q * 4);
                float xs[4] = {xt.x, xt.y, xt.z, xt.w};
#pragma unroll
                for (int j = 0; j < 4; j++) {
                    int jj = q * 4 + j;
                    v[jj] += (double)xs[j];
                    unsigned char ss = (v[jj] >= 1.0) ? 1 : 0;
                    sp.b[jj] = ss;
                    if (ss) v[jj] = 0.0;
                }
            }
            *(uint4*)(Sx + frag_addr(t * S_ + s, d0)) = sp.u;
        }
    }
}

// ---------------------------------------------------------------------------
// 2) i8 MFMA GEMM, exact fixed-point. B LDS-staged with BK=128 (2 k-blocks
//    per barrier, 2x32KB dbuf); A streamed from global fragment order with
//    register rotation. Optional mask: Mp = QKp presence words; prologue
//    OR-reduces 16 copies into an LDS byte mask for this block's t.
//    Tile 128M x 64N; 4 waves 2x2; wave 64M x 32N x 4 planes (128 AGPR acc).
// ---------------------------------------------------------------------------
__global__ __launch_bounds__(256, 2) void k_gemm_i8(
    const unsigned char* __restrict__ A,   // fragment-order spikes
    const unsigned char* __restrict__ Bp,  // packed digit planes (frag order)
    const unsigned int* __restrict__ Mp,   // QKp [16][4][192] words or nullptr
    float* __restrict__ C0, float* __restrict__ C1, float* __restrict__ C2,
    int bzoff) {
    int z = blockIdx.z;
    const unsigned char* B = Bp + (size_t)(bzoff + z) * PLANE_BYTES;
    float* C = (z == 0) ? C0 : (z == 1) ? C1 : C2;

    __shared__ __align__(16) unsigned char bsm[2 * 32768];
    __shared__ __align__(16) unsigned int maskw[192];

    int tid = threadIdx.x;
    int lane = tid & 63;
    int w = tid >> 6;                 // wave 0..3
    int wm = w >> 1;                  // 0..1
    int wn = w & 1;                   // 0..1
    int row0 = blockIdx.x * 128;
    int tI = row0 >> 11;              // uniform t for this block
    int n0 = blockIdx.y * 64;
    int nbg0 = blockIdx.y * 4;
    int col = lane & 15;
    int quad = lane >> 4;

    int32x4 zerov = {0, 0, 0, 0};
    int32x4 acc[4][2][4];             // [mb][nb][p]
#pragma unroll
    for (int mb = 0; mb < 4; mb++)
#pragma unroll
        for (int nb = 0; nb < 2; nb++)
#pragma unroll
            for (int p = 0; p < 4; p++) acc[mb][nb][p] = zerov;

    const unsigned char* Ab =
        A + (size_t)((row0 >> 4) + wm * 4) * 12 * 1024 + lane * 16;

    // stage k-blocks 2*kb2 and 2*kb2+1 into buffer buf
    auto stageB = [&](int buf, int kb2) {
        unsigned char* bb = bsm + buf * 32768;
#pragma unroll
        for (int kk = 0; kk < 2; kk++)
#pragma unroll
            for (int qi = 0; qi < 4; qi++) {
                int q = w * 4 + qi;       // chunk id: p = q>>2, nb = q&3
                int p = q >> 2, nb = q & 3;
                cp16(bb + kk * 16384 + q * 1024,
                     B + (size_t)((p * 48 + nbg0 + nb) * 12 + 2 * kb2 + kk) *
                             1024 + lane * 16);
            }
    };

    stageB(0, 0);
    if (Mp && tid < 192) {
        unsigned int m = 0;
#pragma unroll
        for (int c = 0; c < 16; c++) m |= Mp[c * 768 + tI * 192 + tid];
        maskw[tid] = m;               // bytes in {0,1}
    }
    int32x4 a[2][4];
#pragma unroll
    for (int mb = 0; mb < 4; mb++)
        a[0][mb] = *(const int32x4*)(Ab + (size_t)(mb * 12) * 1024);
    __syncthreads();

    for (int kb2 = 0; kb2 < 6; kb2++) {
        int cur = kb2 & 1;
        if (kb2 < 5) stageB(1 - cur, kb2 + 1);
#pragma unroll
        for (int kbh = 0; kbh < 2; kbh++) {
            int kb = kb2 * 2 + kbh;
            if (kb < 11) {
#pragma unroll
                for (int mb = 0; mb < 4; mb++)
                    a[(kb + 1) & 1][mb] = *(const int32x4*)(
                        Ab + (size_t)(mb * 12 + kb + 1) * 1024);
            }
            int32x4 af[4];
#pragma unroll
            for (int mb = 0; mb < 4; mb++) af[mb] = a[kb & 1][mb];
            if (Mp) {
                int32x4 mv = *(const int32x4*)(
                    (const unsigned char*)maskw + kb * 64 + quad * 16);
#pragma unroll
                for (int mb = 0; mb < 4; mb++) af[mb] &= mv;
            }
            const unsigned char* bb = bsm + cur * 32768 + kbh * 16384;
#pragma unroll
            for (int p = 0; p < 4; p++)
#pragma unroll
                for (int nb = 0; nb < 2; nb++) {
                    int32x4 bf = *(const int32x4*)(
                        bb + (size_t)(p * 4 + wn * 2 + nb) * 1024 + lane * 16);
#pragma unroll
                    for (int mb = 0; mb < 4; mb++)
                        acc[mb][nb][p] = __builtin_amdgcn_mfma_i32_16x16x64_i8(
                            af[mb], bf, acc[mb][nb][p], 0, 0, 0);
                }
        }
        __syncthreads();
    }

#pragma unroll
    for (int mb = 0; mb < 4; mb++)
#pragma unroll
        for (int nb = 0; nb < 2; nb++)
#pragma unroll
            for (int r = 0; r < 4; r++) {
                // exact: digits < 2^17, products/sums exact in double
                double td = (double)acc[mb][nb][0][r]
                          + 256.0 * (double)acc[mb][nb][1][r]
                          + 65536.0 * (double)acc[mb][nb][2][r]
                          + 16777216.0 * (double)acc[mb][nb][3][r];
                float v = (float)(td * (1.0 / 1073741824.0));
                int rr = row0 + wm * 64 + mb * 16 + quad * 4 + r;
                int cc = n0 + wn * 32 + nb * 16 + col;
                C[(size_t)rr * D_ + cc] = v;
            }
}

// ---------------------------------------------------------------------------
// 3) Fused BN + IF for Q,K,V in ONE block per s. Q/K spikes never leave the
//    block: q&k presence bytes are atomicOr'd packed into QKp[s%16] copies.
//    V spikes written int8 fragment-order.
// ---------------------------------------------------------------------------
__global__ __launch_bounds__(256) void k_bnif_qk(const float* __restrict__ Qf,
                                                 const float* __restrict__ Kf,
                                                 const float* __restrict__ Vf,
                                                 unsigned char* __restrict__ Vs,
                                                 unsigned int* __restrict__ QKp) {
    int s = blockIdx.x;
    __shared__ float buf[3][T_][D_];          // 36 KB
    __shared__ double red[8];
    __shared__ unsigned char spkV[T_ * D_];   // 3 KB
    __shared__ unsigned char spkA[T_ * D_];   // 3 KB (q & k)
    __shared__ double stats[3][2];            // mean, rstd per tensor

    int tid = threadIdx.x;
    const float* Xs[3] = {Qf, Kf, Vf};
#pragma unroll
    for (int y = 0; y < 3; y++) {
        double sum = 0.0, sumsq = 0.0;
#pragma unroll
        for (int t = 0; t < T_; t++) {
            for (int d = tid; d < D_; d += 256) {
                float v = Xs[y][(size_t)t * SD_ + (size_t)s * D_ + d];
                buf[y][t][d] = v;
                double dv = (double)v;
                sum += dv;
                sumsq += dv * dv;
            }
        }
#pragma unroll
        for (int off = 32; off > 0; off >>= 1) {
            sum += __shfl_down(sum, off);
            sumsq += __shfl_down(sumsq, off);
        }
        int lane = tid & 63, wv = tid >> 6;
        if (lane == 0) { red[wv] = sum; red[4 + wv] = sumsq; }
        __syncthreads();
        if (tid == 0) {
            double s4 = red[0] + red[1] + red[2] + red[3];
            double q4 = red[4] + red[5] + red[6] + red[7];
            double mean = s4 / 3072.0;
            double var = q4 / 3072.0 - mean * mean;
            stats[y][0] = mean;
            stats[y][1] = 1.0 / sqrt(var + 1e-5);
        }
        __syncthreads();
    }

    for (int d = tid; d < D_; d += 256) {
        unsigned char qs[T_], ks[T_];
#pragma unroll
        for (int y = 0; y < 3; y++) {
            double mean = stats[y][0], rstd = stats[y][1];
            double v = 0.0;
#pragma unroll
            for (int t = 0; t < T_; t++) {
                double xn = ((double)buf[y][t][d] - mean) * rstd;
                v += xn;
                unsigned char sp = (v >= 1.0) ? 1 : 0;
                if (y == 0) qs[t] = sp;
                else if (y == 1) ks[t] = sp;
                else spkV[t * D_ + d] = sp;
                if (sp) v = 0.0;
            }
        }
#pragma unroll
        for (int t = 0; t < T_; t++) spkA[t * D_ + d] = qs[t] & ks[t];
    }
    __syncthreads();

    if (tid < 192) {
        // V spikes -> fragment order (16-byte granules)
        int tt = tid / 48, gg = tid % 48;
        uint4 val = *(const uint4*)&spkV[tt * D_ + gg * 16];
        size_t dst = ((size_t)(tt * 128 + (s >> 4)) * 12 + (gg >> 2)) * 1024 +
                     (size_t)((gg & 3) * 256 + (s & 15) * 16);
        *(uint4*)(Vs + dst) = val;
        // q&k presence -> privatized OR accumulator (packed bytes)
        unsigned int* dstq = QKp + (s & 15) * 768;
#pragma unroll
        for (int t = 0; t < T_; t++) {
            unsigned int word = *(const unsigned int*)&spkA[t * D_ + tid * 4];
            if (word) atomicOr(dstq + t * 192 + tid, word);
        }
    }
}

// ---------------------------------------------------------------------------
// 6) Final BatchNorm1d (fp64 stats), writes fp32 to d_out.
// ---------------------------------------------------------------------------
__global__ __launch_bounds__(256) void k_bn_out(const float* __restrict__ Xin,
                                                float* __restrict__ out) {
    int s = blockIdx.x;
    __shared__ float buf[T_][D_];
    __shared__ double red[16];
    int tid = threadIdx.x;
    double sum = 0.0, sumsq = 0.0;
#pragma unroll
    for (int t = 0; t < T_; t++) {
        for (int d = tid; d < D_; d += 256) {
            float v = Xin[(size_t)t * SD_ + (size_t)s * D_ + d];
            buf[t][d] = v;
            double dv = (double)v;
            sum += dv;
            sumsq += dv * dv;
        }
    }
#pragma unroll
    for (int off = 32; off > 0; off >>= 1) {
        sum += __shfl_down(sum, off);
        sumsq += __shfl_down(sumsq, off);
    }
    int lane = tid & 63, wv = tid >> 6;
    if (lane == 0) { red[wv] = sum; red[4 + wv] = sumsq; }
    __syncthreads();
    if (tid == 0) {
        double s4 = red[0] + red[1] + red[2] + red[3];
        double q4 = red[4] + red[5] + red[6] + red[7];
        double mean = s4 / 3072.0;
        double var = q4 / 3072.0 - mean * mean;
        red[8] = mean;
        red[9] = 1.0 / sqrt(var + 1e-5);
    }
    __syncthreads();
    double mean = red[8], rstd = red[9];
    for (int d = tid; d < D_; d += 256) {
#pragma unroll
        for (int t = 0; t < T_; t++) {
            double v = (double)buf[t][d];
            out[(size_t)t * SD_ + (size_t)s * D_ + d] =
                (float)((v - mean) * rstd);
        }
    }
}

// ---------------------------------------------------------------------------
extern "C" void kernel_launch(void* const* d_in, const int* in_sizes, int n_in,
                              void* d_out, int out_size, void* d_ws,
                              size_t ws_size, hipStream_t stream) {
    const float* x  = (const float*)d_in[0];
    const float* wq = (const float*)d_in[1];
    const float* wk = (const float*)d_in[2];
    const float* wv = (const float*)d_in[3];
    const float* wo = (const float*)d_in[4];
    float* out = (float*)d_out;

    float* ws  = (float*)d_ws;
    float* Qf  = ws;                         // pre-BN Q, then GEMM2 out
    float* Kf  = ws + (size_t)TSD_;
    float* Vf  = ws + (size_t)2 * TSD_;
    unsigned int* QKp = (unsigned int*)(ws + (size_t)3 * TSD_);  // 12288 words
    unsigned char* Sx = (unsigned char*)(QKp + 12288);  // init spikes (frag)
    unsigned char* Vs = Sx + (size_t)TSD_;
    unsigned char* Bp = Vs + (size_t)TSD_;   // packed weights, 9.4 MB

    // 0) pack weights + init spikes + zero QKp
    k_prep_all<<<dim3(576, 5), 256, 0, stream>>>(wq, wk, wv, wo, x, Bp, Sx,
                                                 QKp);
    // 1) Q/K/V GEMMs (A from global frag-order, B LDS dbuf BK=128)
    k_gemm_i8<<<dim3(64, 12, 3), 256, 0, stream>>>(Sx, Bp, nullptr,
                                                   Qf, Kf, Vf, 0);
    // 2) BN + IF for Q,K,V + q&k presence accumulation (one block per s)
    k_bnif_qk<<<S_, 256, 0, stream>>>(Qf, Kf, Vf, Vs, QKp);
    // 3) out_pre = (Vs & mask) @ wo -> Qf  (mask OR-reduced in prologue)
    k_gemm_i8<<<dim3(64, 12, 1), 256, 0, stream>>>(Vs, Bp, QKp, Qf, Qf, Qf, 3);
    // 4) final BN -> d_out
    k_bn_out<<<S_, 256, 0, stream>>>(Qf, out);
}